// Round 3
// baseline (596.629 us; speedup 1.0000x reference)
//
#include <hip/hip_runtime.h>

// Problem constants: B=32, N=8, Lq=256, Ld=512, D=768
#define BB 32
#define NN 8
#define LQ 256
#define LD 512
#define DD 768
#define D4 (DD / 4)                  // 192 float4 per row

#define QCH 8                        // lq chunks in qsum kernel
#define QROWS (LQ / QCH)             // 32 rows per chunk
#define QPART_F4 (QCH * BB * D4)     // 49152 float4 in ws
#define CH 8                         // l-chunks per (b,n) doc
#define LCHUNK (LD / CH)             // 64 rows per block
#define NBLK (BB * NN * CH)          // 2048 docs blocks

typedef float f4 __attribute__((ext_vector_type(4)));

// ---------------------------------------------------------------------------
// Kernel 1: qpart[c][b][d4] = sum of 32 lq rows (float4 columns).
// Also zeroes the completion counter (strictly precedes docs kernel).
// ---------------------------------------------------------------------------
__global__ void __launch_bounds__(192)
qsum_kernel(const f4* __restrict__ q, f4* __restrict__ qpart,
            unsigned* __restrict__ counter) {
    int blk = blockIdx.x;            // 0..255 = b*8 + c
    int b = blk >> 3;
    int c = blk & 7;
    int t = threadIdx.x;             // 0..191 -> float4 column
    if (blk == 0 && t == 0) *counter = 0u;

    const f4* p = q + ((size_t)b * LQ + (size_t)c * QROWS) * D4 + t;
    f4 a0 = 0.f, a1 = 0.f, a2 = 0.f, a3 = 0.f;
    f4 a4 = 0.f, a5 = 0.f, a6 = 0.f, a7 = 0.f;
#pragma unroll
    for (int i = 0; i < QROWS; i += 8) {
        a0 += p[(size_t)(i + 0) * D4];
        a1 += p[(size_t)(i + 1) * D4];
        a2 += p[(size_t)(i + 2) * D4];
        a3 += p[(size_t)(i + 3) * D4];
        a4 += p[(size_t)(i + 4) * D4];
        a5 += p[(size_t)(i + 5) * D4];
        a6 += p[(size_t)(i + 6) * D4];
        a7 += p[(size_t)(i + 7) * D4];
    }
    qpart[((size_t)c * BB + b) * D4 + t] = ((a0 + a1) + (a2 + a3)) + ((a4 + a5) + (a6 + a7));
}

// ---------------------------------------------------------------------------
// Kernel 2: stream docs once (nontemporal), per-block partial, and the LAST
// block to finish reduces all partials and writes the final loss.
// Block = (b,n, l-chunk), 192 threads; thread t owns float4 column d=4t.
// ---------------------------------------------------------------------------
__global__ void __launch_bounds__(192)
docs_kernel(const f4* __restrict__ docs4, const int* __restrict__ is_ans,
            const f4* __restrict__ qpart, float* __restrict__ partials,
            unsigned* __restrict__ counter, float* __restrict__ out) {
    int bn    = blockIdx.x >> 3;     // 0..255
    int chunk = blockIdx.x & 7;      // 0..7
    int b     = bn >> 3;
    int t     = threadIdx.x;

    // qsum fragment for my column (8 L2-resident partials)
    f4 qv = 0.f;
#pragma unroll
    for (int c = 0; c < QCH; ++c)
        qv += qpart[((size_t)c * BB + b) * D4 + t];

    const f4* p = docs4 + ((size_t)bn * LD + (size_t)chunk * LCHUNK) * D4 + t;
    f4 acc = 0.f;
#pragma unroll 8
    for (int l = 0; l < LCHUNK; ++l) {
        f4 v = __builtin_nontemporal_load(&p[(size_t)l * D4]);  // 16B/lane coalesced
        acc += v * qv;
    }
    float s = acc.x + acc.y + acc.z + acc.w;

    // wave-64 reduce, then block reduce (3 waves)
    for (int off = 32; off > 0; off >>= 1)
        s += __shfl_down(s, off, 64);

    __shared__ float wsum[3];
    __shared__ int amLast;
    if ((t & 63) == 0) wsum[t >> 6] = s;
    __syncthreads();
    if (t == 0) {
        float sign = is_ans[bn] ? -1.f : 1.f;
        partials[blockIdx.x] = (wsum[0] + wsum[1] + wsum[2]) * sign;
        __threadfence();                          // release my partial (device scope)
        unsigned old = atomicAdd(counter, 1u);    // device-scope RMW
        amLast = (old == NBLK - 1);
    }
    __syncthreads();
    if (amLast) {
        __threadfence();                          // acquire: invalidate stale L1/L2
        float s2 = 0.f;
        for (int i = t; i < NBLK; i += 192)
            s2 += partials[i];
        for (int off = 32; off > 0; off >>= 1)
            s2 += __shfl_down(s2, off, 64);
        __shared__ float w2[3];
        if ((t & 63) == 0) w2[t >> 6] = s2;
        __syncthreads();
        if (t == 0)
            out[0] = (w2[0] + w2[1] + w2[2]) * (1.f / ((float)LQ * (float)LD));
    }
}

extern "C" void kernel_launch(void* const* d_in, const int* in_sizes, int n_in,
                              void* d_out, int out_size, void* d_ws, size_t ws_size,
                              hipStream_t stream) {
    const f4*  q      = (const f4*)d_in[0];    // [B, Lq, D] f32 as float4
    const f4*  docs4  = (const f4*)d_in[1];    // [B, N, Ld, D] f32 as float4
    const int* is_ans = (const int*)d_in[2];   // [B, N] bool -> int
    float* out = (float*)d_out;

    f4*       qpart    = (f4*)d_ws;                       // [QCH*B*D4] float4
    float*    partials = (float*)(qpart + QPART_F4);      // [NBLK]
    unsigned* counter  = (unsigned*)(partials + NBLK);    // [1]

    qsum_kernel<<<dim3(BB * QCH), 192, 0, stream>>>(q, qpart, counter);
    docs_kernel<<<dim3(NBLK), 192, 0, stream>>>(docs4, is_ans, qpart, partials, counter, out);
}

// Round 4
// 538.656 us; speedup vs baseline: 1.1076x; 1.1076x over previous
//
#include <hip/hip_runtime.h>

// Problem constants: B=32, N=8, Lq=256, Ld=512, D=768
#define BB 32
#define NN 8
#define LQ 256
#define LD 512
#define DD 768
#define D4 (DD / 4)                  // 192 float4 per row

#define QCH 8                        // lq chunks (questions)
#define QROWS (LQ / QCH)             // 32 rows per chunk
#define QBLKS (BB * QCH)             // 256 question blocks
#define QPART_F4 (QCH * BB * D4)     // 49152 f4 in ws

#define CH 8                         // l-chunks per (b,n) doc
#define LCHUNK (LD / CH)             // 64 rows per block
#define DBLKS (BB * NN * CH)         // 2048 doc blocks
#define DPART_F4 (DBLKS * D4)        // 393216 f4 in ws (~6.3 MB)

typedef float f4 __attribute__((ext_vector_type(4)));

// ---------------------------------------------------------------------------
// Kernel A: one launch streams BOTH inputs (no intra-kernel dependency).
//   blocks [0,256):    qpart[c][b][:] = sum of 32 question rows
//   blocks [256,2304): dpart[idx][:]  = sign(bn) * sum of 64 doc rows
// Thread t owns float4 column d=4t. All loads 16B/lane coalesced.
// Block 0 also zeroes d_out (used by kernel B's atomics; kernel-boundary
// visibility — no fences).
// ---------------------------------------------------------------------------
__global__ void __launch_bounds__(192)
stream_kernel(const f4* __restrict__ q, const f4* __restrict__ docs4,
              const int* __restrict__ is_ans,
              f4* __restrict__ qpart, f4* __restrict__ dpart,
              float* __restrict__ out) {
    int blk = blockIdx.x;
    int t   = threadIdx.x;           // 0..191

    if (blk < QBLKS) {
        int b = blk >> 3;
        int c = blk & 7;
        if (blk == 0 && t == 0) out[0] = 0.f;
        const f4* p = q + ((size_t)b * LQ + (size_t)c * QROWS) * D4 + t;
        f4 a0 = 0.f, a1 = 0.f, a2 = 0.f, a3 = 0.f;
        f4 a4 = 0.f, a5 = 0.f, a6 = 0.f, a7 = 0.f;
#pragma unroll
        for (int i = 0; i < QROWS; i += 8) {
            a0 += p[(size_t)(i + 0) * D4];
            a1 += p[(size_t)(i + 1) * D4];
            a2 += p[(size_t)(i + 2) * D4];
            a3 += p[(size_t)(i + 3) * D4];
            a4 += p[(size_t)(i + 4) * D4];
            a5 += p[(size_t)(i + 5) * D4];
            a6 += p[(size_t)(i + 6) * D4];
            a7 += p[(size_t)(i + 7) * D4];
        }
        qpart[((size_t)c * BB + b) * D4 + t] =
            ((a0 + a1) + (a2 + a3)) + ((a4 + a5) + (a6 + a7));
    } else {
        int idx   = blk - QBLKS;     // 0..2047
        int bn    = idx >> 3;        // 0..255
        int chunk = idx & 7;         // 0..7
        const f4* p = docs4 + ((size_t)bn * LD + (size_t)chunk * LCHUNK) * D4 + t;
        f4 acc0 = 0.f, acc1 = 0.f;
#pragma unroll 4
        for (int l = 0; l < LCHUNK; l += 2) {
            acc0 += p[(size_t)(l + 0) * D4];
            acc1 += p[(size_t)(l + 1) * D4];
        }
        float sign = is_ans[bn] ? -1.f : 1.f;
        dpart[(size_t)idx * D4 + t] = (acc0 + acc1) * sign;
    }
}

// ---------------------------------------------------------------------------
// Kernel B: per-b dot product.  Block b (32 blocks x 192 thr):
//   qv = sum_c qpart[c][b][:],  dv = sum over b's 64 dpart vectors,
//   s  = dot(qv, dv); block-reduce; 32 spread atomicAdds into out.
// ~7 MB read total — a few microseconds.
// ---------------------------------------------------------------------------
__global__ void __launch_bounds__(192)
finish_kernel(const f4* __restrict__ qpart, const f4* __restrict__ dpart,
              float* __restrict__ out) {
    int b = blockIdx.x;
    int t = threadIdx.x;

    f4 qv = 0.f;
#pragma unroll
    for (int c = 0; c < QCH; ++c)
        qv += qpart[((size_t)c * BB + b) * D4 + t];

    f4 dv = 0.f;
#pragma unroll 8
    for (int i = 0; i < NN * CH; ++i)
        dv += dpart[(size_t)(b * NN * CH + i) * D4 + t];

    f4 m = qv * dv;
    float s = m.x + m.y + m.z + m.w;
    for (int off = 32; off > 0; off >>= 1)
        s += __shfl_down(s, off, 64);

    __shared__ float wsum[3];
    if ((t & 63) == 0) wsum[t >> 6] = s;
    __syncthreads();
    if (t == 0)
        atomicAdd(out, (wsum[0] + wsum[1] + wsum[2]) * (1.f / ((float)LQ * (float)LD)));
}

extern "C" void kernel_launch(void* const* d_in, const int* in_sizes, int n_in,
                              void* d_out, int out_size, void* d_ws, size_t ws_size,
                              hipStream_t stream) {
    const f4*  q      = (const f4*)d_in[0];    // [B, Lq, D] f32
    const f4*  docs4  = (const f4*)d_in[1];    // [B, N, Ld, D] f32
    const int* is_ans = (const int*)d_in[2];   // [B, N] bool -> int
    float* out = (float*)d_out;

    f4* qpart = (f4*)d_ws;                     // [QCH*B*D4]
    f4* dpart = qpart + QPART_F4;              // [DBLKS*D4]

    stream_kernel<<<dim3(QBLKS + DBLKS), 192, 0, stream>>>(q, docs4, is_ans, qpart, dpart, out);
    finish_kernel<<<dim3(BB), 192, 0, stream>>>(qpart, dpart, out);
}